// Round 1
// baseline (214.516 us; speedup 1.0000x reference)
//
#include <hip/hip_runtime.h>
#include <math.h>

#define NB 64
#define NQ 900
#define NC 91
#define TB_THR 0.9f
#define TC_THR 0.2f
#define EPSF 1e-9f
#define LGEPS 1e-6f

#define NWG_PER_B 8
#define EDGE_THREADS 256

// ---------------- union-find (lock-free, hooks larger root under smaller) ----
__device__ __forceinline__ int uf_find(int* p, int x) {
    volatile int* vp = (volatile int*)p;
    int px = vp[x];
    while (px != x) { x = px; px = vp[x]; }
    return x;
}

__device__ void uf_unite(int* p, int a, int b) {
    while (true) {
        a = uf_find(p, a);
        b = uf_find(p, b);
        if (a == b) return;
        int hi = a > b ? a : b;
        int lo = a ^ b ^ hi;
        if (atomicCAS(&p[hi], hi, lo) == hi) return;
        a = hi; b = lo;  // p[hi] changed under us; retry
    }
}

// ---------------- K1: per-row sums/entropy, init parent & cnt ----------------
__global__ void k_init(const float* __restrict__ logits,
                       float* __restrict__ s, float* __restrict__ ent,
                       int* __restrict__ parent, int* __restrict__ cnt) {
    int idx = blockIdx.x * blockDim.x + threadIdx.x;
    if (idx >= NB * NQ) return;
    const float* row = logits + (size_t)idx * NC;
    float ssum = 0.f;
    for (int c = 0; c < NC; ++c) {
        float pv = 1.f / (1.f + expf(-row[c]));
        ssum += pv;
    }
    float denom = ssum + EPSF;
    float e = 0.f;
    for (int c = 0; c < NC; ++c) {
        float pv = 1.f / (1.f + expf(-row[c]));
        float q = pv / denom;
        e += q * logf(q + EPSF);
    }
    s[idx] = ssum;
    ent[idx] = e;
    parent[idx] = idx;
    cnt[idx] = 0;
}

// ---------------- K2: pairwise GIoU + gated KL -> union ---------------------
__global__ __launch_bounds__(EDGE_THREADS)
void k_edges(const float* __restrict__ bboxes, const float* __restrict__ logits,
             const float* __restrict__ s, const float* __restrict__ ent,
             int* __restrict__ parent) {
    __shared__ float4 box[NQ];   // xyxy
    __shared__ float  ar[NQ];
    int b  = blockIdx.x / NWG_PER_B;
    int wg = blockIdx.x % NWG_PER_B;
    const float* bb = bboxes + (size_t)b * NQ * 4;
    for (int i = threadIdx.x; i < NQ; i += EDGE_THREADS) {
        float4 v = ((const float4*)bb)[i];   // cx cy w h
        float x1 = v.x - 0.5f * v.z, y1 = v.y - 0.5f * v.w;
        float x2 = v.x + 0.5f * v.z, y2 = v.y + 0.5f * v.w;
        box[i] = make_float4(x1, y1, x2, y2);
        ar[i]  = (x2 - x1) * (y2 - y1);
    }
    __syncthreads();

    const long long NP = (long long)NQ * (NQ - 1) / 2;  // 404550
    const int TOT = NWG_PER_B * EDGE_THREADS;           // 2048
    int slot = wg * EDGE_THREADS + threadIdx.x;
    long long chunk = (NP + TOT - 1) / TOT;             // 198
    long long p0 = (long long)slot * chunk;
    if (p0 >= NP) return;
    long long p1 = p0 + chunk; if (p1 > NP) p1 = NP;

    // decode p0 -> (i,j): base(i) = i*(1799-i)/2
    int i = (int)((1799.0 - sqrt(1799.0 * 1799.0 - 8.0 * (double)p0)) * 0.5);
    if (i < 0) i = 0; if (i > NQ - 2) i = NQ - 2;
    while ((long long)(i + 1) * (1799 - (i + 1)) / 2 <= p0) ++i;
    while ((long long)i * (1799 - i) / 2 > p0) --i;
    int j = i + 1 + (int)(p0 - (long long)i * (1799 - i) / 2);

    float4 bi = box[i];
    float  ai = ar[i];

    for (long long p = p0; p < p1; ++p) {
        float4 bj = box[j];
        float  aj = ar[j];
        float ltx = fmaxf(bi.x, bj.x), lty = fmaxf(bi.y, bj.y);
        float rbx = fminf(bi.z, bj.z), rby = fminf(bi.w, bj.w);
        float w = fmaxf(rbx - ltx, 0.f), h = fmaxf(rby - lty, 0.f);
        float inter = w * h;
        float uni = ai + aj - inter;
        float iou = inter / (uni + EPSF);
        float ex = fmaxf(fmaxf(bi.z, bj.z) - fminf(bi.x, bj.x), 0.f);
        float ey = fmaxf(fmaxf(bi.w, bj.w) - fminf(bi.y, bj.y), 0.f);
        float ae = ex * ey;
        float giou = iou - (ae - uni) / (ae + EPSF);
        if (giou > TB_THR) {
            int gi = b * NQ + i, gj = b * NQ + j;
            const float* li = logits + (size_t)gi * NC;
            const float* lj = logits + (size_t)gj * NC;
            float di = s[gi] + EPSF, dj = s[gj] + EPSF;
            float dotij = 0.f, dotji = 0.f;
            for (int c = 0; c < NC; ++c) {
                float pi = 1.f / (1.f + expf(-li[c]));
                float pj = 1.f / (1.f + expf(-lj[c]));
                float qi = pi / di, qj = pj / dj;
                float lqi = logf(qi + EPSF), lqj = logf(qj + EPSF);
                dotij += qi * lqj;
                dotji += qj * lqi;
            }
            bool edge = (ent[gi] - dotij < TC_THR) || (ent[gj] - dotji < TC_THR);
            if (edge) uf_unite(parent, gi, gj);
        }
        if (++j == NQ) { ++i; j = i + 1; bi = box[i]; ai = ar[i]; }
    }
}

// ---------------- K3: flatten labels, count component sizes -----------------
__global__ void k_flatten(const int* __restrict__ parent,
                          int* __restrict__ label, int* __restrict__ cnt) {
    int idx = blockIdx.x * blockDim.x + threadIdx.x;
    if (idx >= NB * NQ) return;
    int r = idx;
    while (parent[r] != r) r = parent[r];
    label[idx] = r;
    atomicAdd(&cnt[r], 1);
}

// ---------------- K4: zero output -------------------------------------------
__global__ void k_zero(float4* __restrict__ out, int n4) {
    int idx = blockIdx.x * blockDim.x + threadIdx.x;
    if (idx < n4) out[idx] = make_float4(0.f, 0.f, 0.f, 0.f);
}

// ---------------- K5: scatter (store for singletons, atomic otherwise) ------
__global__ void k_scatter(const float* __restrict__ bboxes,
                          const float* __restrict__ logits,
                          const int* __restrict__ label, const int* __restrict__ cnt,
                          float* __restrict__ out) {
    long long idx = (long long)blockIdx.x * blockDim.x + threadIdx.x;
    const long long NBB = (long long)NB * NQ * 4;        // 230400
    const long long NTOT = NBB + (long long)NB * NQ * NC; // 5472000
    if (idx >= NTOT) return;
    if (idx < NBB) {
        int g = (int)(idx >> 2);
        int k = (int)(idx & 3);
        int r = label[g];
        float v = bboxes[idx];
        if (r == g && cnt[g] == 1) out[idx] = v;
        else atomicAdd(&out[(size_t)r * 4 + k], v);
    } else {
        long long t = idx - NBB;
        int c = (int)(t % NC);
        int g = (int)(t / NC);
        int r = label[g];
        float v = 1.f / (1.f + expf(-logits[t]));
        if (r == g && cnt[g] == 1) out[idx] = v;
        else atomicAdd(&out[NBB + (size_t)r * NC + c], v);
    }
}

// ---------------- K6: finalize (divide, clip, logit) ------------------------
__global__ void k_finalize(const int* __restrict__ cnt, float* __restrict__ out) {
    long long idx = (long long)blockIdx.x * blockDim.x + threadIdx.x;
    const long long NBB = (long long)NB * NQ * 4;
    const long long NTOT = NBB + (long long)NB * NQ * NC;
    if (idx >= NTOT) return;
    if (idx < NBB) {
        int g = (int)(idx >> 2);
        float d = fmaxf((float)cnt[g], 1.f);
        out[idx] = out[idx] / d;
    } else {
        long long t = idx - NBB;
        int g = (int)(t / NC);
        float d = fmaxf((float)cnt[g], 1.f);
        float v = out[idx] / d;
        v = fminf(fmaxf(v, LGEPS), 1.f - LGEPS);
        out[idx] = logf(v) - log1pf(-v);
    }
}

extern "C" void kernel_launch(void* const* d_in, const int* in_sizes, int n_in,
                              void* d_out, int out_size, void* d_ws, size_t ws_size,
                              hipStream_t stream) {
    const float* bboxes = (const float*)d_in[0];   // [64,900,4] f32
    const float* logits = (const float*)d_in[1];   // [64,900,91] f32
    float* out = (float*)d_out;                    // [230400 bbox] + [5241600 logits]

    char* ws = (char*)d_ws;
    const int NROWS = NB * NQ;                     // 57600
    float* s      = (float*)(ws);
    float* ent    = (float*)(ws + 1 * NROWS * 4);
    int*   parent = (int*)  (ws + 2 * NROWS * 4);
    int*   label  = (int*)  (ws + 3 * NROWS * 4);
    int*   cnt    = (int*)  (ws + 4 * NROWS * 4);

    const int TB = 256;
    int rowBlocks = (NROWS + TB - 1) / TB;         // 225
    k_init<<<rowBlocks, TB, 0, stream>>>(logits, s, ent, parent, cnt);

    k_edges<<<NB * NWG_PER_B, EDGE_THREADS, 0, stream>>>(bboxes, logits, s, ent, parent);

    k_flatten<<<rowBlocks, TB, 0, stream>>>(parent, label, cnt);

    const long long NTOT = (long long)NB * NQ * (4 + NC);   // 5472000
    int n4 = (int)(NTOT / 4);                               // 1368000
    k_zero<<<(n4 + TB - 1) / TB, TB, 0, stream>>>((float4*)out, n4);

    int sBlocks = (int)((NTOT + TB - 1) / TB);
    k_scatter<<<sBlocks, TB, 0, stream>>>(bboxes, logits, label, cnt, out);

    k_finalize<<<sBlocks, TB, 0, stream>>>(cnt, out);
}